// Round 9
// baseline (86.417 us; speedup 1.0000x reference)
//
#include <hip/hip_runtime.h>

// Mamba-2 SSD forward. B=2, L=4096, H=16, P=S=64, chunk=64, n=64 chunks.
// K1 (ssd_k1): LDS-FREE, BARRIER-FREE per-chunk frontend (K3-shaped):
//   mm1: CB = C·B^T direct global fragment loads; Cs = E∘C from same regs;
//        M = L∘CB frag-native store.
//   mmH: D[s][p] = sum_c B^T[s][c]·(dte∘X)[c][p] via scalar column-gather
//        fragments (16-lane groups read full 64B lines); dte via dynamic shfl.
// K2 (ssd_scan): element-wise inter-chunk scan on frag-native hws (4-deep pipeline).
// K3 (ssd_k3): unchanged (proven ~12us): LDS-free, barrier-free.

#define BSZ 2
#define LSEQ 4096
#define NH 16
#define NC 64
#define NCH (BSZ * NH * NC)      // 2048 chunk tasks
#define SCAN_G 8
#define CHW 4096                 // ushort elems per chunk ws tile
#define TILE_USHORTS ((size_t)NCH * CHW)

typedef float f32x4 __attribute__((ext_vector_type(4)));
typedef __bf16 bf16x8 __attribute__((ext_vector_type(8)));

union FragU { uint4 u; bf16x8 b; unsigned short s[8]; };

__device__ __forceinline__ unsigned short f2b(float x) {
    union { float f; unsigned u; } c; c.f = x;
    unsigned r = c.u + 0x7fffu + ((c.u >> 16) & 1u);   // RNE bf16
    return (unsigned short)(r >> 16);
}
__device__ __forceinline__ float b2f(unsigned short v) {
    union { unsigned u; float f; } c; c.u = ((unsigned)v) << 16;
    return c.f;
}

__device__ __forceinline__ bf16x8 pack8(const float4 a, const float4 b) {
    FragU f;
    f.s[0] = f2b(a.x); f.s[1] = f2b(a.y); f.s[2] = f2b(a.z); f.s[3] = f2b(a.w);
    f.s[4] = f2b(b.x); f.s[5] = f2b(b.y); f.s[6] = f2b(b.z); f.s[7] = f2b(b.w);
    return f.b;
}
__device__ __forceinline__ bf16x8 pack8s(const float4 a, const float4 b, float sc) {
    FragU f;
    f.s[0] = f2b(a.x * sc); f.s[1] = f2b(a.y * sc); f.s[2] = f2b(a.z * sc); f.s[3] = f2b(a.w * sc);
    f.s[4] = f2b(b.x * sc); f.s[5] = f2b(b.y * sc); f.s[6] = f2b(b.z * sc); f.s[7] = f2b(b.w * sc);
    return f.b;
}

// ---------------- K1: LDS-free, barrier-free frontend ----------------
__global__ __launch_bounds__(256) void ssd_k1(
    const float* __restrict__ Xg, const float* __restrict__ Ag,
    const float* __restrict__ Bg, const float* __restrict__ Cg,
    unsigned short* __restrict__ hws, unsigned short* __restrict__ Mws,
    unsigned short* __restrict__ Csws, float* __restrict__ dws)
{
    const int tid = threadIdx.x;
    const int l = tid & 63;
    const int w = tid >> 6;
    const int n = blockIdx.x & (NC - 1);
    const int h = (blockIdx.x >> 6) & (NH - 1);
    const int b = blockIdx.x >> 10;
    const int row0 = b * LSEQ + n * 64;
    const unsigned chb = (unsigned)blockIdx.x * CHW;
    const int i15 = l & 15;
    const int e4 = l >> 4;
    const int s0 = e4 << 3;          // k-group base (8-contig)

    // --- A gather + per-wave inclusive cumsum ---
    float acs = Ag[(unsigned)(row0 + l) * NH + h];
    #pragma unroll
    for (int off = 1; off < 64; off <<= 1) {
        float v = __shfl_up(acs, off, 64);
        if (l >= off) acs += v;
    }
    const float a63 = __shfl(acs, 63, 64);
    if (tid == 63) dws[blockIdx.x] = a63;   // log chunk decay

    // --- A-op fragments ---
    // mm1 A-op: B row j = w*16+i15, k = s contiguous (vector loads)
    const int j = w * 16 + i15;
    bf16x8 aB[2];
    #pragma unroll
    for (int kk = 0; kk < 2; ++kk) {
        const unsigned g = ((unsigned)(row0 + j) * NH + h) * 64 + kk * 32 + s0;
        aB[kk] = pack8(*(const float4*)&Bg[g], *(const float4*)&Bg[g + 4]);
    }
    // mmH A-op: B^T row s = w*16+i15, k = c (scalar column-gather; 4 full lines/instr)
    bf16x8 aBt[2];
    #pragma unroll
    for (int kk = 0; kk < 2; ++kk) {
        FragU f;
        #pragma unroll
        for (int e = 0; e < 8; ++e) {
            const int c = kk * 32 + s0 + e;
            f.s[e] = f2b(Bg[((unsigned)(row0 + c) * NH + h) * 64 + j]);
        }
        aBt[kk] = f.b;
    }

    // --- decay factors ---
    float Ei4[4];
    #pragma unroll
    for (int ti = 0; ti < 4; ++ti) Ei4[ti] = __expf(__shfl(acs, ti * 16 + i15, 64));
    const int il = e4 << 2;
    const int j0 = w * 16 + il;
    float Rj[4];
    #pragma unroll
    for (int r = 0; r < 4; ++r) Rj[r] = __expf(-__shfl(acs, j0 + r, 64));
    // dte for this lane's k-slots: c = kk*32 + s0 + e
    float dte[16];
    #pragma unroll
    for (int kk = 0; kk < 2; ++kk)
        #pragma unroll
        for (int e = 0; e < 8; ++e)
            dte[kk * 8 + e] = __expf(a63 - __shfl(acs, kk * 32 + s0 + e, 64));

    // --- mm1: D[j][i] = sum_s B[j][s] C[i][s]; Cs = Ei∘C from the same regs ---
    const f32x4 zero = {0.f, 0.f, 0.f, 0.f};
    f32x4 accT[4] = {zero, zero, zero, zero};
    #pragma unroll
    for (int kk = 0; kk < 2; ++kk) {
        #pragma unroll
        for (int ti = 0; ti < 4; ++ti) {
            const int i = ti * 16 + i15;
            const unsigned g = ((unsigned)(row0 + i) * NH + h) * 64 + kk * 32 + s0;
            const float4 c0 = *(const float4*)&Cg[g];
            const float4 c1 = *(const float4*)&Cg[g + 4];
            accT[ti] = __builtin_amdgcn_mfma_f32_16x16x32_bf16(aB[kk], pack8(c0, c1), accT[ti], 0, 0, 0);
            FragU cs; cs.b = pack8s(c0, c1, Ei4[ti]);
            *(uint4*)&Csws[chb + (((kk * 4 + ti) * 64 + l) << 3)] = cs.u;   // contiguous
        }
    }

    // --- M epilogue: M[i][j] = (i>=j) ? Ei*Rj*CB : 0, frag-native contiguous store ---
    #pragma unroll
    for (int ti = 0; ti < 4; ++ti) {
        const int i = ti * 16 + i15;
        const float Ei = Ei4[ti];
        ushort4 m;
        m.x = (i >= j0 + 0) ? f2b(Ei * Rj[0] * accT[ti][0]) : (unsigned short)0;
        m.y = (i >= j0 + 1) ? f2b(Ei * Rj[1] * accT[ti][1]) : (unsigned short)0;
        m.z = (i >= j0 + 2) ? f2b(Ei * Rj[2] * accT[ti][2]) : (unsigned short)0;
        m.w = (i >= j0 + 3) ? f2b(Ei * Rj[3] * accT[ti][3]) : (unsigned short)0;
        *(ushort4*)&Mws[chb + (((ti * 4 + w) * 64 + l) << 2)] = m;
    }

    // --- mmH: D[s][p] = sum_c B^T[s][c]·(dte∘X)[c][p], X via scalar column-gather ---
    f32x4 accH[4] = {zero, zero, zero, zero};
    #pragma unroll
    for (int kk = 0; kk < 2; ++kk) {
        #pragma unroll
        for (int tp = 0; tp < 4; ++tp) {
            const int p = tp * 16 + i15;
            FragU xf;
            #pragma unroll
            for (int e = 0; e < 8; ++e) {
                const int c = kk * 32 + s0 + e;
                xf.s[e] = f2b(Xg[((unsigned)(row0 + c) * NH + h) * 64 + p] * dte[kk * 8 + e]);
            }
            accH[tp] = __builtin_amdgcn_mfma_f32_16x16x32_bf16(aBt[kk], xf.b, accH[tp], 0, 0, 0);
        }
    }

    // h store, fragment-native: elem (p=tp*16+(l&15), s=w*16+il+r)
    const int kk2 = w >> 1;
    const int q3 = ((w & 1) << 1) | (il >> 3);
    const int e0 = il & 7;
    const int lt = q3 * 16 + i15;
    #pragma unroll
    for (int tp = 0; tp < 4; ++tp) {
        ushort4 o;
        o.x = f2b(accH[tp][0]); o.y = f2b(accH[tp][1]);
        o.z = f2b(accH[tp][2]); o.w = f2b(accH[tp][3]);
        *(ushort4*)&hws[chb + (((kk2 * 4 + tp) * 64 + lt) << 3) + e0] = o;
    }
}

// ---------------- K2: element-wise scan over chunks (in-place, coalesced) ----------------
__global__ __launch_bounds__(256) void ssd_scan(unsigned short* __restrict__ hws,
                                                const float* __restrict__ dws)
{
    __shared__ float sD[NC];
    const int tid = threadIdx.x;
    const int bh = blockIdx.x / SCAN_G;
    const int g = blockIdx.x % SCAN_G;
    if (tid < NC) sD[tid] = __expf(dws[bh * NC + tid]);   // chunk decay from log
    __syncthreads();

    unsigned* hw32 = (unsigned*)hws;
    const unsigned base = (unsigned)bh * NC * 2048u + g * 256u + tid;

    unsigned buf[4];
    #pragma unroll
    for (int jj = 0; jj < 4; ++jj) buf[jj] = hw32[base + jj * 2048u];

    float cx = 0.f, cy = 0.f;
    #pragma unroll 4
    for (int c = 0; c < NC; ++c) {
        const unsigned cur = buf[c & 3];
        if (c + 4 < NC) buf[c & 3] = hw32[base + (unsigned)(c + 4) * 2048u];
        hw32[base + (unsigned)c * 2048u] = (unsigned)f2b(cx) | ((unsigned)f2b(cy) << 16);
        const float d = sD[c];
        cx = d * cx + b2f((unsigned short)(cur & 0xffffu));
        cy = d * cy + b2f((unsigned short)(cur >> 16));
    }
}

// ---------------- K3: LDS-free, barrier-free (unchanged) ----------------
__global__ __launch_bounds__(256) void ssd_k3(
    const float* __restrict__ Xg, const unsigned short* __restrict__ Mws,
    const unsigned short* __restrict__ Csws, const unsigned short* __restrict__ hws,
    float* __restrict__ Yg)
{
    const int tid = threadIdx.x;
    const int l = tid & 63;
    const int w = tid >> 6;
    const int n = blockIdx.x & (NC - 1);
    const int h = (blockIdx.x >> 6) & (NH - 1);
    const int b = blockIdx.x >> 10;
    const int row0 = b * LSEQ + n * 64;
    const unsigned chb = (unsigned)blockIdx.x * CHW;
    const int i15 = l & 15;
    const int p = w * 16 + i15;

    bf16x8 aX[2], aH[2];
    #pragma unroll
    for (int kk = 0; kk < 2; ++kk) {
        const int c0 = kk * 32 + ((l >> 4) << 3);
        bf16x8 x;
        #pragma unroll
        for (int e = 0; e < 8; ++e)
            x[e] = (__bf16)Xg[((unsigned)(row0 + c0 + e) * NH + h) * 64 + p];
        aX[kk] = x;
        FragU f; f.u = *(const uint4*)&hws[chb + (((kk * 4 + w) * 64 + l) << 3)];
        aH[kk] = f.b;
    }

    const f32x4 zero = {0.f, 0.f, 0.f, 0.f};
    f32x4 accY[4] = {zero, zero, zero, zero};
    f32x4 accI[4] = {zero, zero, zero, zero};
    #pragma unroll
    for (int kk = 0; kk < 2; ++kk) {
        const int j0 = kk * 32 + ((l >> 4) << 3);
        const int wj = j0 >> 4;
        const int q = (j0 >> 2) & 3;
        #pragma unroll
        for (int ti = 0; ti < 4; ++ti) {
            FragU mf, cf;
            *(ushort4*)&mf.s[0] = *(const ushort4*)&Mws[chb + (((ti * 4 + wj) * 64 + q * 16 + i15) << 2)];
            *(ushort4*)&mf.s[4] = *(const ushort4*)&Mws[chb + (((ti * 4 + wj) * 64 + (q + 1) * 16 + i15) << 2)];
            cf.u = *(const uint4*)&Csws[chb + (((kk * 4 + ti) * 64 + l) << 3)];
            accY[ti] = __builtin_amdgcn_mfma_f32_16x16x32_bf16(aX[kk], mf.b, accY[ti], 0, 0, 0);
            accI[ti] = __builtin_amdgcn_mfma_f32_16x16x32_bf16(aH[kk], cf.b, accI[ti], 0, 0, 0);
        }
    }

    const int pbase = w * 16 + ((l >> 4) << 2);
    #pragma unroll
    for (int ti = 0; ti < 4; ++ti) {
        const int i = ti * 16 + i15;
        float4 o;
        o.x = accY[ti][0] + accI[ti][0];
        o.y = accY[ti][1] + accI[ti][1];
        o.z = accY[ti][2] + accI[ti][2];
        o.w = accY[ti][3] + accI[ti][3];
        *(float4*)&Yg[((unsigned)(row0 + i) * NH + h) * 64 + pbase] = o;
    }
}

extern "C" void kernel_launch(void* const* d_in, const int* in_sizes, int n_in,
                              void* d_out, int out_size, void* d_ws, size_t ws_size,
                              hipStream_t stream) {
    const float* X = (const float*)d_in[0];
    const float* A = (const float*)d_in[1];
    const float* Bm = (const float*)d_in[2];
    const float* Cm = (const float*)d_in[3];
    float* Y = (float*)d_out;
    unsigned short* hws = (unsigned short*)d_ws;        // 16.8 MB
    unsigned short* Mws = hws + TILE_USHORTS;           // 16.8 MB
    unsigned short* Csws = Mws + TILE_USHORTS;          // 16.8 MB
    float* dws = (float*)(Csws + TILE_USHORTS);         // 8 KB (log chunk decays)

    ssd_k1<<<NCH, 256, 0, stream>>>(X, A, Bm, Cm, hws, Mws, Csws, dws);
    ssd_scan<<<BSZ * NH * SCAN_G, 256, 0, stream>>>(hws, dws);
    ssd_k3<<<NCH, 256, 0, stream>>>(X, Mws, Csws, hws, Y);
}

// Round 10
// 70.780 us; speedup vs baseline: 1.2209x; 1.2209x over previous
//
#include <hip/hip_runtime.h>

// Mamba-2 SSD forward. B=2, L=4096, H=16, P=S=64, chunk=64, n=64 chunks.
// R10 = R3 structure (best measured: 57.3us) + validated deltas only:
//   ssd_hfinal: exact R3 component. h_final^T -> hws [p][s] bf16, chunk decay.
//   ssd_scan:   R3 scan + 4-deep prefetch (R6-validated).
//   ssd_y:      R3's fat Y kernel, rebuilt Y-orientation: ONE barrier.
//               mm1 CB=C.B^T (wave owns i-slab) -> M=L∘CB written into own sC slab
//               -> mm2 M.X + mm3 C.h (aC regs reused), dfs exact in fp32 epilogue.

#define BSZ 2
#define LSEQ 4096
#define NH 16
#define NC 64
#define NCH (BSZ * NH * NC)
#define SCAN_G 8
#define CHW 4096                 // ushort elems per chunk hws tile
#define TILE_USHORTS ((size_t)NCH * CHW)

typedef float f32x4 __attribute__((ext_vector_type(4)));
typedef __bf16 bf16x8 __attribute__((ext_vector_type(8)));

union FragU { uint4 u; bf16x8 b; unsigned short s[8]; };

__device__ __forceinline__ unsigned short f2b(float x) {
    union { float f; unsigned u; } c; c.f = x;
    unsigned r = c.u + 0x7fffu + ((c.u >> 16) & 1u);   // RNE bf16
    return (unsigned short)(r >> 16);
}
__device__ __forceinline__ float b2f(unsigned short v) {
    union { unsigned u; float f; } c; c.u = ((unsigned)v) << 16;
    return c.f;
}

// LDS element-index swizzles, 64 ushort per row (XOR col bits 3..5; 8-groups stay aligned)
__device__ __forceinline__ int rm_e(int row, int k) { return row * 64 + (k ^ ((row & 7) << 3)); }
__device__ __forceinline__ int tr_e(int row, int k) { return row * 64 + (k ^ (((row >> 1) & 7) << 3)); }

__device__ __forceinline__ bf16x8 frag_rm(const unsigned short* buf, int tile, int kk, int l) {
    FragU f; f.u = *(const uint4*)&buf[rm_e(tile * 16 + (l & 15), kk * 32 + ((l >> 4) << 3))];
    return f.b;
}
__device__ __forceinline__ bf16x8 frag_tr(const unsigned short* buf, int tile, int kk, int l) {
    FragU f; f.u = *(const uint4*)&buf[tr_e(tile * 16 + (l & 15), kk * 32 + ((l >> 4) << 3))];
    return f.b;
}

// ---------------- K1: h_final (exact R3 component) ----------------
__global__ __launch_bounds__(256) void ssd_hfinal(
    const float* __restrict__ Xg, const float* __restrict__ Ag,
    const float* __restrict__ Bg, unsigned short* __restrict__ hws,
    float* __restrict__ dws)
{
    __shared__ __align__(16) unsigned short sBt[64 * 64];  // B^T [s][c]
    __shared__ __align__(16) unsigned short sXt[64 * 64];  // (dte∘X)^T [p][c]
    __shared__ float sDte[64];

    const int tid = threadIdx.x;
    const int l = tid & 63;
    const int w = tid >> 6;
    const int n = blockIdx.x & (NC - 1);
    const int h = (blockIdx.x >> 6) & (NH - 1);
    const int b = blockIdx.x >> 10;
    const int row0 = b * LSEQ + n * 64;
    const unsigned chb = (unsigned)blockIdx.x * CHW;
    const int p0 = (tid & 15) * 4;

    float4 xv[4], bv[4];
    #pragma unroll
    for (int it = 0; it < 4; ++it) {
        const int c = (tid >> 4) + it * 16;
        const unsigned g = ((unsigned)(row0 + c) * NH + h) * 64 + p0;
        xv[it] = *(const float4*)&Xg[g];
        bv[it] = *(const float4*)&Bg[g];
    }
    if (tid < 64) {
        float a = Ag[(unsigned)(row0 + tid) * NH + h];
        #pragma unroll
        for (int off = 1; off < 64; off <<= 1) {
            float v = __shfl_up(a, off, 64);
            if (tid >= off) a += v;
        }
        const float a63 = __shfl(a, 63, 64);
        sDte[tid] = __expf(a63 - a);
        if (tid == 63) dws[blockIdx.x] = __expf(a63);
    }
    __syncthreads();

    #pragma unroll
    for (int it = 0; it < 4; ++it) {
        const int c = (tid >> 4) + it * 16;
        const float dte = sDte[c];
        sBt[tr_e(p0 + 0, c)] = f2b(bv[it].x);
        sBt[tr_e(p0 + 1, c)] = f2b(bv[it].y);
        sBt[tr_e(p0 + 2, c)] = f2b(bv[it].z);
        sBt[tr_e(p0 + 3, c)] = f2b(bv[it].w);
        sXt[tr_e(p0 + 0, c)] = f2b(xv[it].x * dte);
        sXt[tr_e(p0 + 1, c)] = f2b(xv[it].y * dte);
        sXt[tr_e(p0 + 2, c)] = f2b(xv[it].z * dte);
        sXt[tr_e(p0 + 3, c)] = f2b(xv[it].w * dte);
    }
    __syncthreads();

    const f32x4 zero = {0.f, 0.f, 0.f, 0.f};
    f32x4 acc[4] = {zero, zero, zero, zero};
    #pragma unroll
    for (int kk = 0; kk < 2; ++kk) {
        const bf16x8 aB = frag_tr(sBt, w, kk, l);
        #pragma unroll
        for (int tp = 0; tp < 4; ++tp)
            acc[tp] = __builtin_amdgcn_mfma_f32_16x16x32_bf16(aB, frag_tr(sXt, tp, kk, l), acc[tp], 0, 0, 0);
    }

    // hws layout [chunk][p][s]: s = 16w + (l>>4)*4 + r, p = tp*16 + (l&15)
    const int sbase = w * 16 + ((l >> 4) << 2);
    #pragma unroll
    for (int tp = 0; tp < 4; ++tp) {
        const int p = tp * 16 + (l & 15);
        ushort4 o;
        o.x = f2b(acc[tp][0]); o.y = f2b(acc[tp][1]);
        o.z = f2b(acc[tp][2]); o.w = f2b(acc[tp][3]);
        *(ushort4*)&hws[chb + (unsigned)p * 64 + sbase] = o;
    }
}

// ---------------- K2: element-wise scan over chunks (in-place, 4-deep) ----------------
__global__ __launch_bounds__(256) void ssd_scan(unsigned short* __restrict__ hws,
                                                const float* __restrict__ dws)
{
    __shared__ float sD[NC];
    const int tid = threadIdx.x;
    const int bh = blockIdx.x / SCAN_G;
    const int g = blockIdx.x % SCAN_G;
    if (tid < NC) sD[tid] = dws[bh * NC + tid];
    __syncthreads();

    unsigned* hw32 = (unsigned*)hws;
    const unsigned base = (unsigned)bh * NC * 2048u + g * 256u + tid;

    unsigned buf[4];
    #pragma unroll
    for (int jj = 0; jj < 4; ++jj) buf[jj] = hw32[base + jj * 2048u];

    float cx = 0.f, cy = 0.f;
    #pragma unroll 4
    for (int c = 0; c < NC; ++c) {
        const unsigned cur = buf[c & 3];
        if (c + 4 < NC) buf[c & 3] = hw32[base + (unsigned)(c + 4) * 2048u];
        hw32[base + (unsigned)c * 2048u] = (unsigned)f2b(cx) | ((unsigned)f2b(cy) << 16);
        const float d = sD[c];
        cx = d * cx + b2f((unsigned short)(cur & 0xffffu));
        cy = d * cy + b2f((unsigned short)(cur >> 16));
    }
}

// ---------------- K3: Y = M.X + dfs∘(C.h_inter), ONE barrier ----------------
__global__ __launch_bounds__(256) void ssd_y(
    const float* __restrict__ Xg, const float* __restrict__ Ag,
    const float* __restrict__ Bg, const float* __restrict__ Cg,
    const unsigned short* __restrict__ hws, float* __restrict__ Yg)
{
    __shared__ __align__(16) unsigned short sB[64 * 64];   // B rm [j][s]
    __shared__ __align__(16) unsigned short sC[64 * 64];   // C rm [i][s]; slab w becomes M rows
    __shared__ __align__(16) unsigned short sXt[64 * 64];  // X^T [p][j]
    __shared__ __align__(16) unsigned short sHt[64 * 64];  // h_inter^T rm [p][s]
    __shared__ float sE[64], sR[64];

    const int tid = threadIdx.x;
    const int l = tid & 63;
    const int w = tid >> 6;
    const int n = blockIdx.x & (NC - 1);
    const int h = (blockIdx.x >> 6) & (NH - 1);
    const int b = blockIdx.x >> 10;
    const int row0 = b * LSEQ + n * 64;
    const unsigned chb = (unsigned)blockIdx.x * CHW;
    const int i15 = l & 15;
    const int p0 = (tid & 15) * 4;

    // --- issue global loads early ---
    float4 xv[4], bv[4], cv[4];
    #pragma unroll
    for (int it = 0; it < 4; ++it) {
        const int c = (tid >> 4) + it * 16;
        const unsigned g = ((unsigned)(row0 + c) * NH + h) * 64 + p0;
        xv[it] = *(const float4*)&Xg[g];
        bv[it] = *(const float4*)&Bg[g];
        cv[it] = *(const float4*)&Cg[g];
    }
    const int pr = tid >> 2;
    const int sh0 = (tid & 3) << 4;
    const uint4 h0 = *(const uint4*)&hws[chb + (unsigned)pr * 64 + sh0];
    const uint4 h1 = *(const uint4*)&hws[chb + (unsigned)pr * 64 + sh0 + 8];

    // --- wave0: cumsum of A -> sE (exp), sR (exp-neg) ---
    if (tid < 64) {
        float a = Ag[(unsigned)(row0 + tid) * NH + h];
        #pragma unroll
        for (int off = 1; off < 64; off <<= 1) {
            float v = __shfl_up(a, off, 64);
            if (tid >= off) a += v;
        }
        sE[tid] = __expf(a);
        sR[tid] = __expf(-a);
    }

    // --- stage tiles ---
    #pragma unroll
    for (int it = 0; it < 4; ++it) {
        const int c = (tid >> 4) + it * 16;
        ushort4 bw; bw.x = f2b(bv[it].x); bw.y = f2b(bv[it].y); bw.z = f2b(bv[it].z); bw.w = f2b(bv[it].w);
        ushort4 cw; cw.x = f2b(cv[it].x); cw.y = f2b(cv[it].y); cw.z = f2b(cv[it].z); cw.w = f2b(cv[it].w);
        *(ushort4*)&sB[rm_e(c, p0)] = bw;
        *(ushort4*)&sC[rm_e(c, p0)] = cw;
        sXt[tr_e(p0 + 0, c)] = f2b(xv[it].x);
        sXt[tr_e(p0 + 1, c)] = f2b(xv[it].y);
        sXt[tr_e(p0 + 2, c)] = f2b(xv[it].z);
        sXt[tr_e(p0 + 3, c)] = f2b(xv[it].w);
    }
    *(uint4*)&sHt[rm_e(pr, sh0)] = h0;
    *(uint4*)&sHt[rm_e(pr, sh0 + 8)] = h1;
    __syncthreads();   // the only barrier

    // --- aC fragments (own slab w), reused for mm1 and mm3; sC slab w then dead ---
    bf16x8 aC[2];
    #pragma unroll
    for (int kk = 0; kk < 2; ++kk) aC[kk] = frag_rm(sC, w, kk, l);

    // --- mm1: CB[i][j] = sum_s C[i][s] B[j][s]; wave w owns i in [16w,16w+16) ---
    const f32x4 zero = {0.f, 0.f, 0.f, 0.f};
    f32x4 accT[4] = {zero, zero, zero, zero};
    #pragma unroll
    for (int kk = 0; kk < 2; ++kk) {
        #pragma unroll
        for (int tj = 0; tj < 4; ++tj)
            accT[tj] = __builtin_amdgcn_mfma_f32_16x16x32_bf16(aC[kk], frag_rm(sB, tj, kk, l), accT[tj], 0, 0, 0);
    }

    // --- M = L∘CB written into OWN sC slab (in-wave dep only, no barrier) ---
    const int il = (l >> 4) << 2;
    float Ei[4];
    #pragma unroll
    for (int r = 0; r < 4; ++r) Ei[r] = sE[w * 16 + il + r];
    #pragma unroll
    for (int tj = 0; tj < 4; ++tj) {
        const int j = tj * 16 + i15;
        const float Rj = sR[j];
        #pragma unroll
        for (int r = 0; r < 4; ++r) {
            const int i = w * 16 + il + r;
            const float v = (i >= j) ? Ei[r] * Rj * accT[tj][r] : 0.f;
            sC[i * 64 + (j ^ ((i & 7) << 3))] = f2b(v);
        }
    }

    // --- mm2: Y = M.X ; mm3: I = C.h (aC reused) ---
    f32x4 accY[4] = {zero, zero, zero, zero};
    f32x4 accI[4] = {zero, zero, zero, zero};
    #pragma unroll
    for (int kk = 0; kk < 2; ++kk) {
        const bf16x8 aM = frag_rm(sC, w, kk, l);   // own slab: rows 16w..16w+15
        #pragma unroll
        for (int tp = 0; tp < 4; ++tp) {
            accY[tp] = __builtin_amdgcn_mfma_f32_16x16x32_bf16(aM, frag_tr(sXt, tp, kk, l), accY[tp], 0, 0, 0);
            accI[tp] = __builtin_amdgcn_mfma_f32_16x16x32_bf16(aC[kk], frag_rm(sHt, tp, kk, l), accI[tp], 0, 0, 0);
        }
    }

    // --- epilogue: Y[i][p] = accY + E_i * accI (fp32-exact dfs) ---
    #pragma unroll
    for (int tp = 0; tp < 4; ++tp) {
        const int p = tp * 16 + i15;
        #pragma unroll
        for (int r = 0; r < 4; ++r) {
            const int i = w * 16 + il + r;
            Yg[((unsigned)(row0 + i) * NH + h) * 64 + p] = accY[tp][r] + Ei[r] * accI[tp][r];
        }
    }
}

extern "C" void kernel_launch(void* const* d_in, const int* in_sizes, int n_in,
                              void* d_out, int out_size, void* d_ws, size_t ws_size,
                              hipStream_t stream) {
    const float* X = (const float*)d_in[0];
    const float* A = (const float*)d_in[1];
    const float* Bm = (const float*)d_in[2];
    const float* Cm = (const float*)d_in[3];
    float* Y = (float*)d_out;
    unsigned short* hws = (unsigned short*)d_ws;   // 16.8 MB
    float* dws = (float*)(hws + TILE_USHORTS);     // 8 KB (chunk decays, exp form)

    ssd_hfinal<<<NCH, 256, 0, stream>>>(X, A, Bm, hws, dws);
    ssd_scan<<<BSZ * NH * SCAN_G, 256, 0, stream>>>(hws, dws);
    ssd_y<<<NCH, 256, 0, stream>>>(X, A, Bm, Cm, hws, Y);
}